// Round 2
// baseline (667.496 us; speedup 1.0000x reference)
//
#include <hip/hip_runtime.h>

#define CROP_H 14
#define CROP_W 14
#define NBOX   512
#define CH     256
#define IMH    200
#define IMW    200
#define PLANE   (IMH * IMW)                 // 40000 floats per channel plane
#define NPOS    (CROP_H * CROP_W)           // 196 sample positions per box
#define PER_BOX (CH * NPOS)                 // 50176
#define CGROUPS 8                           // channel groups per box
#define CPG     (CH / CGROUPS)              // 32 channels per block
#define NROWS   (2 * CROP_H)                // 28 staged rows (y0,y0+1 per gy)
#define F4_PER_CH (CROP_H * 2 * (IMW / 4))  // 1400 float4 staged per channel

// Row-staged gather: the scattered bilinear taps cost ~25 KB of 64B-line
// traffic per (box,channel) anyway, so instead stage the 28 needed rows
// (22.4 KB) with fully COALESCED float4 loads into LDS, then gather taps
// from LDS. This converts 51M scattered 8B global loads (the measured
// limiter: ~110K lines/CU through the L1-miss path at L2 latency) into
// 2.9M coalesced wave-loads + cheap LDS reads.
// Grid (box=x fastest, cgroup=y): same-channel staging across boxes is
// co-resident -> L3 absorbs cross-box row reuse, HBM fetch ~= image once.
__global__ __launch_bounds__(256, 7) void CropAndResize_60146722013533_kernel(
    const float* __restrict__ image,
    const float* __restrict__ boxes,
    const int*   __restrict__ box_idx,
    float*       __restrict__ out)
{
    const int n  = blockIdx.x;          // box index (fastest dispatch dim)
    const int cg = blockIdx.y;          // channel group
    const int t  = threadIdx.x;

    __shared__ float slds[NROWS][IMW];  // 28 rows x 200 floats = 22.4 KB
    __shared__ int   sy0[CROP_H], sy1r[CROP_H];   // y0 and min(y0+1,199)
    __shared__ float sly[CROP_H], slx[CROP_W];
    __shared__ int   svy[CROP_H], svx[CROP_W];
    __shared__ int   sx0[CROP_W], sx1[CROP_W];
    __shared__ int   sb;

    // ---- per-box geometry, computed once ----
    if (t < CROP_H + CROP_W) {
        const float by1 = boxes[n * 4 + 0];
        const float bx1 = boxes[n * 4 + 1];
        const float by2 = boxes[n * 4 + 2];
        const float bx2 = boxes[n * 4 + 3];
        if (t < CROP_H) {
            const int gy = t;
            float h_scale = (by2 - by1) * (float)(IMH - 1) / (float)(CROP_H - 1);
            float in_y = by1 * (float)(IMH - 1) + (float)gy * h_scale;
            svy[gy] = (in_y >= 0.0f && in_y <= (float)(IMH - 1)) ? 1 : 0;
            float yf = floorf(in_y);
            sly[gy] = in_y - yf;
            int y0 = (int)fminf(fmaxf(yf, 0.0f), (float)(IMH - 1));
            sy0[gy]  = y0;
            sy1r[gy] = (y0 < IMH - 1) ? (y0 + 1) : (IMH - 1);
        } else {
            const int gx = t - CROP_H;
            float w_scale = (bx2 - bx1) * (float)(IMW - 1) / (float)(CROP_W - 1);
            float in_x = bx1 * (float)(IMW - 1) + (float)gx * w_scale;
            svx[gx] = (in_x >= 0.0f && in_x <= (float)(IMW - 1)) ? 1 : 0;
            float xf = floorf(in_x);
            slx[gx] = in_x - xf;
            sx0[gx] = (int)fminf(fmaxf(xf, 0.0f), (float)(IMW - 1));
            sx1[gx] = (int)fminf(fmaxf(ceilf(in_x), 0.0f), (float)(IMW - 1));
        }
    }
    if (t == 0) sb = box_idx[n];
    __syncthreads();

    // ---- hoist gather-side params into registers (position-resident) ----
    const int gy = t / CROP_W;          // valid for t < 196
    const int gx = t - gy * CROP_W;
    int   x0 = 0, x1i = 0, vmask = 0, rowt = 0;
    float ly = 0.0f, lx = 0.0f;
    if (t < NPOS) {
        x0    = sx0[gx];
        x1i   = sx1[gx];
        ly    = sly[gy];
        lx    = slx[gx];
        vmask = svy[gy] & svx[gx];
        rowt  = 2 * gy;                 // staged top row; bottom = rowt+1
    }

    const float* pb = image + (size_t)(sb * CH + cg * CPG) * (size_t)PLANE;
    float*       o  = out + (size_t)n * PER_BOX + (size_t)(cg * CPG) * NPOS + t;

    for (int c = 0; c < CPG; ++c) {
        // ---- stage: 14 row-pairs, 1400 coalesced float4 loads ----
        #pragma unroll
        for (int k = t; k < F4_PER_CH; k += 256) {
            const int gyr  = k / 100;            // 0..13
            const int w    = k - gyr * 100;      // 0..99
            const int half = (w >= 50) ? 1 : 0;  // 0: y0 row, 1: y0+1 row
            const int wq   = w - half * 50;      // float4 index in row, 0..49
            const int row  = half ? sy1r[gyr] : sy0[gyr];
            float4 v;
            __builtin_memcpy(&v, pb + (size_t)row * IMW + wq * 4, 16);
            *(float4*)&slds[gyr * 2 + half][wq * 4] = v;
        }
        __syncthreads();

        // ---- gather from LDS ----
        if (t < NPOS) {
            const float tl = slds[rowt    ][x0];
            const float tr = slds[rowt    ][x1i];
            const float bl = slds[rowt + 1][x0];
            const float br = slds[rowt + 1][x1i];
            const float top = tl + (tr - tl) * lx;
            const float bot = bl + (br - bl) * lx;
            float val = top + (bot - top) * ly;
            if (!vmask) val = 0.0f;
            __builtin_nontemporal_store(val, o);
        }
        __syncthreads();                // lds reusable next channel

        pb += PLANE;
        o  += NPOS;
    }
}

extern "C" void kernel_launch(void* const* d_in, const int* in_sizes, int n_in,
                              void* d_out, int out_size, void* d_ws, size_t ws_size,
                              hipStream_t stream) {
    const float* image   = (const float*)d_in[0];
    const float* boxes   = (const float*)d_in[1];
    const int*   box_idx = (const int*)d_in[2];
    float* out = (float*)d_out;

    dim3 grid(NBOX, CGROUPS, 1);   // x = box (fastest), y = channel group
    dim3 block(256, 1, 1);
    CropAndResize_60146722013533_kernel<<<grid, block, 0, stream>>>(image, boxes, box_idx, out);
}

// Round 3
// 488.282 us; speedup vs baseline: 1.3670x; 1.3670x over previous
//
#include <hip/hip_runtime.h>

#define CROP_H 14
#define CROP_W 14
#define NBOX   512
#define CH     256
#define IMH    200
#define IMW    200
#define PLANE   (IMH * IMW)
#define NPOS    (CROP_H * CROP_W)          // 196
#define PER_BOX (CH * NPOS)                // 50176
#define CHUNK   512                        // elems per block (2 per thread)
#define NCHUNKS (PER_BOX / CHUNK)          // 98

// Round-0 structure (the best measured: ~167us) + 2 elems/thread for ILP.
// Grid (box=x fastest, chunk=y): resident blocks cover a ~10-channel slice
// of ALL boxes (~13 MB) -> scattered bilinear taps stay L2/L3-resident.
// Each thread issues 4 independent 8B tap-loads before any use (2 elems x
// 2 row-pairs), doubling outstanding scattered loads vs round-0.
// Nontemporal stores keep the 103 MB output stream out of L2.
__global__ __launch_bounds__(256, 8) void CropAndResize_60146722013533_kernel(
    const float* __restrict__ image,
    const float* __restrict__ boxes,
    const int*   __restrict__ box_idx,
    float*       __restrict__ out)
{
    const int n = blockIdx.x;          // box index (fastest dispatch dim)
    const int t = threadIdx.x;

    __shared__ int   sy0[CROP_H], sy1[CROP_H], sx0[CROP_W], sx1[CROP_W];
    __shared__ float sly[CROP_H], slx[CROP_W];
    __shared__ int   svy[CROP_H], svx[CROP_W];
    __shared__ int   sb;

    if (t < CROP_H + CROP_W) {
        const float by1 = boxes[n * 4 + 0];
        const float bx1 = boxes[n * 4 + 1];
        const float by2 = boxes[n * 4 + 2];
        const float bx2 = boxes[n * 4 + 3];
        if (t < CROP_H) {
            const int gy = t;
            float h_scale = (by2 - by1) * (float)(IMH - 1) / (float)(CROP_H - 1);
            float in_y = by1 * (float)(IMH - 1) + (float)gy * h_scale;
            svy[gy] = (in_y >= 0.0f && in_y <= (float)(IMH - 1)) ? 1 : 0;
            float yf = floorf(in_y);
            sly[gy] = in_y - yf;
            sy0[gy] = (int)fminf(fmaxf(yf, 0.0f), (float)(IMH - 1));
            sy1[gy] = (int)fminf(fmaxf(ceilf(in_y), 0.0f), (float)(IMH - 1));
        } else {
            const int gx = t - CROP_H;
            float w_scale = (bx2 - bx1) * (float)(IMW - 1) / (float)(CROP_W - 1);
            float in_x = bx1 * (float)(IMW - 1) + (float)gx * w_scale;
            svx[gx] = (in_x >= 0.0f && in_x <= (float)(IMW - 1)) ? 1 : 0;
            float xf = floorf(in_x);
            slx[gx] = in_x - xf;
            sx0[gx] = (int)fminf(fmaxf(xf, 0.0f), (float)(IMW - 1));
            sx1[gx] = (int)fminf(fmaxf(ceilf(in_x), 0.0f), (float)(IMW - 1));
        }
    }
    if (t == 0) sb = box_idx[n];
    __syncthreads();

    const int base = blockIdx.y * CHUNK;
    const float* __restrict__ img = image + (size_t)sb * CH * PLANE;
    float* __restrict__ ob = out + (size_t)n * PER_BOX + base + t;

    // ---- element 0 and element 1 (independent; loads issued together) ----
    const int elem0 = base + t;
    const int elem1 = elem0 + 256;

    // elem 0 geometry
    const int c0  = elem0 / NPOS;
    const int r0  = elem0 - c0 * NPOS;
    const int gy0 = r0 / CROP_W;
    const int gx0 = r0 - gy0 * CROP_W;
    const int x0a = sx0[gx0];
    const int xb0 = (x0a < IMW - 2) ? x0a : (IMW - 2);
    const float* p0 = img + (size_t)c0 * PLANE;
    const float* rt0 = p0 + sy0[gy0] * IMW + xb0;
    const float* rb0 = p0 + sy1[gy0] * IMW + xb0;

    // elem 1 geometry
    const int c1  = elem1 / NPOS;
    const int r1  = elem1 - c1 * NPOS;
    const int gy1 = r1 / CROP_W;
    const int gx1 = r1 - gy1 * CROP_W;
    const int x1a = sx0[gx1];
    const int xb1 = (x1a < IMW - 2) ? x1a : (IMW - 2);
    const float* p1 = img + (size_t)c1 * PLANE;
    const float* rt1 = p1 + sy0[gy1] * IMW + xb1;
    const float* rb1 = p1 + sy1[gy1] * IMW + xb1;

    // issue all 4 scattered 8B loads before any use
    float2 vt0, vb0, vt1, vb1;
    __builtin_memcpy(&vt0, rt0, 8);
    __builtin_memcpy(&vb0, rb0, 8);
    __builtin_memcpy(&vt1, rt1, 8);
    __builtin_memcpy(&vb1, rb1, 8);

    // ---- elem 0 math ----
    {
        const int   x1i = sx1[gx0];
        const float ly  = sly[gy0];
        const float lx  = slx[gx0];
        const float tl = (x0a == xb0) ? vt0.x : vt0.y;
        const float tr = (x1i == xb0) ? vt0.x : vt0.y;
        const float bl = (x0a == xb0) ? vb0.x : vb0.y;
        const float br = (x1i == xb0) ? vb0.x : vb0.y;
        const float top = tl + (tr - tl) * lx;
        const float bot = bl + (br - bl) * lx;
        float val = top + (bot - top) * ly;
        if (!(svy[gy0] & svx[gx0])) val = 0.0f;
        __builtin_nontemporal_store(val, ob);
    }
    // ---- elem 1 math ----
    {
        const int   x1i = sx1[gx1];
        const float ly  = sly[gy1];
        const float lx  = slx[gx1];
        const float tl = (x1a == xb1) ? vt1.x : vt1.y;
        const float tr = (x1i == xb1) ? vt1.x : vt1.y;
        const float bl = (x1a == xb1) ? vb1.x : vb1.y;
        const float br = (x1i == xb1) ? vb1.x : vb1.y;
        const float top = tl + (tr - tl) * lx;
        const float bot = bl + (br - bl) * lx;
        float val = top + (bot - top) * ly;
        if (!(svy[gy1] & svx[gx1])) val = 0.0f;
        __builtin_nontemporal_store(val, ob + 256);
    }
}

extern "C" void kernel_launch(void* const* d_in, const int* in_sizes, int n_in,
                              void* d_out, int out_size, void* d_ws, size_t ws_size,
                              hipStream_t stream) {
    const float* image   = (const float*)d_in[0];
    const float* boxes   = (const float*)d_in[1];
    const int*   box_idx = (const int*)d_in[2];
    float* out = (float*)d_out;

    dim3 grid(NBOX, NCHUNKS, 1);   // x = box (fastest), y = 512-elem chunk
    dim3 block(256, 1, 1);
    CropAndResize_60146722013533_kernel<<<grid, block, 0, stream>>>(image, boxes, box_idx, out);
}